// Round 1
// baseline (1749.956 us; speedup 1.0000x reference)
//
#include <hip/hip_runtime.h>

#define DIV_UP(a,b) (((a)+(b)-1)/(b))
#define DEC_NWG 33

__device__ __forceinline__ float sigm(float x){ return 1.f/(1.f+__expf(-x)); }
__device__ __forceinline__ float tanh_f(float x){ return 1.f - 2.f/(__expf(2.f*x)+1.f); }

__device__ __forceinline__ void fma4x4(const float4 wv, const float4 xv, float acc[4][4]){
  acc[0][0] += wv.x*xv.x; acc[0][1] += wv.x*xv.y; acc[0][2] += wv.x*xv.z; acc[0][3] += wv.x*xv.w;
  acc[1][0] += wv.y*xv.x; acc[1][1] += wv.y*xv.y; acc[1][2] += wv.y*xv.z; acc[1][3] += wv.y*xv.w;
  acc[2][0] += wv.z*xv.x; acc[2][1] += wv.z*xv.y; acc[2][2] += wv.z*xv.z; acc[2][3] += wv.z*xv.w;
  acc[3][0] += wv.w*xv.x; acc[3][1] += wv.w*xv.y; acc[3][2] += wv.w*xv.z; acc[3][3] += wv.w*xv.w;
}

// ---------------- setup: zero barrier counter + ybuf(2x576) + cinit(528) ----------------
__global__ void k_setup(float* zreg, int n, int* cnt){
  int idx = threadIdx.x;
  if (idx == 0) *cnt = 0;
  for (int i = idx; i < n; i += 256) zreg[i] = 0.f;
}

// ---------------- pool1: 4x4/4 maxpool (32,128,128)->(32,32,32) ----------------
__global__ void k_pool1(const float* __restrict__ src, float* __restrict__ out){
  int idx = blockIdx.x*256 + threadIdx.x;
  if (idx >= 32*32*32) return;
  int x = idx & 31, y = (idx>>5)&31, c = idx>>10;
  const float* p = src + ((size_t)(c*128) + y*4)*128 + x*4;
  float m = -1e30f;
  #pragma unroll
  for (int i=0;i<4;i++)
    #pragma unroll
    for (int j=0;j<4;j++) m = fmaxf(m, p[i*128+j]);
  out[idx] = m;
}

// ---------------- conv as im2col-GEMM, 64oc x 64px tile, K-split G ----------------
template<int KS>
__global__ __launch_bounds__(256) void k_conv_gemm(
    const float* __restrict__ in, const float* __restrict__ w,
    float* __restrict__ part,
    int Cin, int Hin, int Win, int Cout, int Hout, int Wout, int G, int kchunk)
{
  const int P = Hout*Wout;
  const int K = Cin*KS*KS;
  const int pxT = (P+63)>>6;
  int b = blockIdx.x;
  const int g = b % G; b /= G;
  const int pt = b % pxT; const int ot = b / pxT;
  const int k0 = g*kchunk;
  const int k1 = min(K, k0+kchunk);
  const int tid = threadIdx.x;
  const int tx = tid & 15, ty = tid >> 4;
  const int sp = tid & 63, sk = tid >> 6;
  int p_st = pt*64 + sp;
  bool pv = p_st < P;
  int pys = 0, pxs = 0;
  if (pv){ pys = p_st / Wout; pxs = p_st - pys*Wout; }
  __shared__ __align__(16) float Xs[16][64];
  __shared__ __align__(16) float Ws[16][68];
  float acc[4][4];
  #pragma unroll
  for (int i=0;i<4;i++)
    #pragma unroll
    for (int j=0;j<4;j++) acc[i][j]=0.f;
  for (int kb=k0; kb<k1; kb+=16){
    #pragma unroll
    for (int i=0;i<4;i++){
      int k = kb + sk + i*4;
      float v = 0.f;
      if (k < k1 && pv){
        int ic = k/(KS*KS); int t = k - ic*(KS*KS); int ky = t/KS, kx = t - ky*KS;
        v = in[((size_t)(ic*Hin) + pys+ky)*Win + (pxs+kx)];
      }
      Xs[sk+i*4][sp] = v;
    }
    #pragma unroll
    for (int i=0;i<4;i++){
      int k = kb + tx;
      int oc = ot*64 + ty + i*16;
      Ws[tx][ty+i*16] = (k < k1) ? w[(size_t)oc*K + k] : 0.f;
    }
    __syncthreads();
    #pragma unroll
    for (int kk=0;kk<16;kk++){
      float4 wv = *(const float4*)&Ws[kk][ty*4];
      float4 xv = *(const float4*)&Xs[kk][tx*4];
      fma4x4(wv, xv, acc);
    }
    __syncthreads();
  }
  float* po = part + (size_t)g*Cout*P;
  #pragma unroll
  for (int i=0;i<4;i++){
    int oc = ot*64 + ty*4 + i;
    #pragma unroll
    for (int j=0;j<4;j++){
      int p = pt*64 + tx*4 + j;
      if (p < P) po[(size_t)oc*P + p] = acc[i][j];
    }
  }
}

__global__ void k_conv_reduce(const float* __restrict__ part, const float* __restrict__ bias,
                              float* __restrict__ out, int Cout, int P, int G){
  int idx = blockIdx.x*256 + threadIdx.x;
  int total = Cout*P;
  if (idx >= total) return;
  int oc = idx / P;
  float s = bias[oc];
  for (int g=0; g<G; g++) s += part[(size_t)g*total + idx];
  out[idx] = fmaxf(s, 0.f);
}

// ---------------- pool2: 3x3/2 maxpool (512,21,21)->(512,10,10) flat ----------------
__global__ void k_pool2(const float* __restrict__ in, float* __restrict__ out){
  int idx = blockIdx.x*256 + threadIdx.x;
  if (idx >= 51200) return;
  int x = idx % 10; int y = (idx/10)%10; int c = idx/100;
  const float* p = in + ((size_t)(c*21) + y*2)*21 + x*2;
  float m = -1e30f;
  #pragma unroll
  for (int i=0;i<3;i++)
    #pragma unroll
    for (int j=0;j<3;j++) m = fmaxf(m, p[i*21+j]);
  out[idx] = m;
}

// ---------------- fc matvec: one row per block ----------------
__global__ __launch_bounds__(256) void k_fc(const float* __restrict__ w, const float* __restrict__ x,
                     const float* __restrict__ b, float* __restrict__ out, int N, int do_relu){
  int row = blockIdx.x;
  int tid = threadIdx.x;
  const float* wr = w + (size_t)row*N;
  float s = 0.f;
  for (int i = tid*4; i < N; i += 1024){
    float4 wv = *(const float4*)(wr + i);
    float4 xv = *(const float4*)(x + i);
    s += wv.x*xv.x + wv.y*xv.y + wv.z*xv.z + wv.w*xv.w;
  }
  #pragma unroll
  for (int off=32; off; off>>=1) s += __shfl_xor(s, off, 64);
  __shared__ float red[4];
  if ((tid & 63) == 0) red[tid>>6] = s;
  __syncthreads();
  if (tid == 0){
    float t = red[0]+red[1]+red[2]+red[3] + b[row];
    if (do_relu) t = fmaxf(t, 0.f);
    out[row] = t;
  }
}

// ---------------- C = [dec_wih_f; dec_wih_b](2056x257) @ lin_w(257x514) ----------------
__global__ __launch_bounds__(256) void k_gemm_wl(
    const float* __restrict__ wf, const float* __restrict__ wb,
    const float* __restrict__ lw, float* __restrict__ C)
{
  int b = blockIdx.x;
  int nt = b % 9; int mt = b / 9;   // 33 x 9 tiles
  int tid = threadIdx.x;
  int tx = tid&15, ty = tid>>4;
  int sp = tid&63, sk = tid>>6;
  __shared__ __align__(16) float Xs[16][64];
  __shared__ __align__(16) float Ws[16][68];
  float acc[4][4];
  #pragma unroll
  for (int i=0;i<4;i++)
    #pragma unroll
    for (int j=0;j<4;j++) acc[i][j]=0.f;
  for (int kb=0; kb<257; kb+=16){
    #pragma unroll
    for (int i=0;i<4;i++){
      int k = kb+sk+i*4;
      int col = nt*64 + sp;
      Xs[sk+i*4][sp] = (k<257 && col<514) ? lw[(size_t)k*514+col] : 0.f;
    }
    #pragma unroll
    for (int i=0;i<4;i++){
      int k = kb+tx;
      int row = mt*64 + ty + i*16;
      float v = 0.f;
      if (k<257 && row<2056)
        v = (row<1028) ? wf[(size_t)row*257+k] : wb[(size_t)(row-1028)*257+k];
      Ws[tx][ty+i*16] = v;
    }
    __syncthreads();
    #pragma unroll
    for (int kk=0;kk<16;kk++){
      float4 wv = *(const float4*)&Ws[kk][ty*4];
      float4 xv = *(const float4*)&Xs[kk][tx*4];
      fma4x4(wv, xv, acc);
    }
    __syncthreads();
  }
  #pragma unroll
  for (int i=0;i<4;i++){
    int row = mt*64 + ty*4 + i;
    #pragma unroll
    for (int j=0;j<4;j++){
      int col = nt*64 + tx*4 + j;
      if (row<2056 && col<514) C[(size_t)row*514+col] = acc[i][j];
    }
  }
}

// ---------------- assemble A[u][g][576] = C + Whh block (zero-padded) ----------------
__global__ void k_assemble(const float* __restrict__ C, const float* __restrict__ whf,
                           const float* __restrict__ whb, float* __restrict__ A){
  int idx = blockIdx.x*256+threadIdx.x;
  if (idx >= 528*4*576) return;
  int k = idx % 576;
  int g = (idx/576)&3;
  int u = idx/2304;
  float v = 0.f;
  if (u < 514 && k < 514){
    int j = (u<257)? u : u-257;
    int row = ((u<257)?0:1028) + g*257 + j;
    v = C[(size_t)row*514 + k];
    if (u<257){ if (k<257) v += whf[(size_t)(g*257+j)*257 + k]; }
    else      { if (k>=257) v += whb[(size_t)(g*257+j)*257 + (k-257)]; }
  }
  A[idx] = v;
}

// ---------------- d[u][g] = wih_row . lin_b + bih + bhh (zero-padded) ----------------
__global__ void k_dvec(const float* __restrict__ wihf, const float* __restrict__ wihb,
                       const float* __restrict__ bihf, const float* __restrict__ bhhf,
                       const float* __restrict__ bihb, const float* __restrict__ bhhb,
                       const float* __restrict__ lb, float* __restrict__ dv){
  int idx = blockIdx.x*256+threadIdx.x;
  if (idx >= 528*4) return;
  int u = idx>>2, g = idx&3;
  float v = 0.f;
  if (u < 514){
    int j = (u<257)? u : u-257;
    int r = g*257+j;
    const float* wr = ((u<257)? wihf : wihb) + (size_t)r*257;
    v = (u<257) ? (bihf[r]+bhhf[r]) : (bihb[r]+bhhb[r]);
    for (int m=0;m<257;m++) v += wr[m]*lb[m];
  }
  dv[idx]=v;
}

// ---------------- encoder (h0=c0=0 so whh term vanishes) ----------------
__global__ void k_enc_gates(const float* __restrict__ wf, const float* __restrict__ wb,
                            const float* __restrict__ bihf, const float* __restrict__ bhhf,
                            const float* __restrict__ bihb, const float* __restrict__ bhhb,
                            const float* __restrict__ feat, float* __restrict__ gates){
  __shared__ float fs[128];
  int tid = threadIdx.x;
  if (tid < 128) fs[tid] = feat[tid];
  __syncthreads();
  int r = blockIdx.x*256 + tid;
  if (r >= 2056) return;
  const float* wr; float bias;
  if (r < 1028){ wr = wf + (size_t)r*128; bias = bihf[r]+bhhf[r]; }
  else { int rr = r-1028; wr = wb + (size_t)rr*128; bias = bihb[rr]+bhhb[rr]; }
  float s = bias;
  for (int m=0;m<128;m++) s += wr[m]*fs[m];
  gates[r] = s;
}

__global__ void k_enc_point(const float* __restrict__ gates, float* __restrict__ y0,
                            float* __restrict__ cinit){
  int u = blockIdx.x*256+threadIdx.x;
  if (u >= 514) return;
  int j = (u<257)? u : u-257;
  int base = (u<257)? 0 : 1028;
  float gi = gates[base + j];
  float gg = gates[base + 514 + j];
  float go = gates[base + 771 + j];
  float c = sigm(gi)*tanh_f(gg);
  float h = sigm(go)*tanh_f(c);
  y0[u] = h; cinit[u] = c;
}

// ---------------- persistent fused decoder: 128 steps, 1 device sync/step ----------------
__global__ __launch_bounds__(256) void k_decode(
    const float* __restrict__ A, const float* __restrict__ dv,
    const float* __restrict__ cinit, float* __restrict__ ybuf,
    float* __restrict__ Yh, int* __restrict__ cnt)
{
  const int tid = threadIdx.x;
  const int u = blockIdx.x*16 + (tid>>4);
  const int q = tid & 15;
  float w[4][36];
  {
    const float* base = A + (size_t)u*4*576 + q*36;
    #pragma unroll
    for (int g=0; g<4; g++){
      #pragma unroll
      for (int i=0;i<36;i+=4){
        float4 v = *(const float4*)(base + g*576 + i);
        w[g][i]=v.x; w[g][i+1]=v.y; w[g][i+2]=v.z; w[g][i+3]=v.w;
      }
    }
  }
  const float4 dg = *(const float4*)(dv + u*4);
  float c = cinit[u];
  __shared__ __align__(16) float ys[576];
  for (int step=0; step<128; step++){
    const float* yin = ybuf + (step&1)*576;
    float* yout = ybuf + ((step+1)&1)*576;
    for (int i=tid; i<576; i+=256)
      ys[i] = __hip_atomic_load(yin+i, __ATOMIC_RELAXED, __HIP_MEMORY_SCOPE_AGENT);
    __syncthreads();
    float s0=0.f, s1=0.f, s2=0.f, s3=0.f;
    const float4* yl4 = (const float4*)&ys[q*36];
    #pragma unroll
    for (int i=0;i<9;i++){
      float4 yv = yl4[i];
      s0 += w[0][i*4]*yv.x + w[0][i*4+1]*yv.y + w[0][i*4+2]*yv.z + w[0][i*4+3]*yv.w;
      s1 += w[1][i*4]*yv.x + w[1][i*4+1]*yv.y + w[1][i*4+2]*yv.z + w[1][i*4+3]*yv.w;
      s2 += w[2][i*4]*yv.x + w[2][i*4+1]*yv.y + w[2][i*4+2]*yv.z + w[2][i*4+3]*yv.w;
      s3 += w[3][i*4]*yv.x + w[3][i*4+1]*yv.y + w[3][i*4+2]*yv.z + w[3][i*4+3]*yv.w;
    }
    #pragma unroll
    for (int off=8; off; off>>=1){
      s0 += __shfl_xor(s0, off, 64);
      s1 += __shfl_xor(s1, off, 64);
      s2 += __shfl_xor(s2, off, 64);
      s3 += __shfl_xor(s3, off, 64);
    }
    if (q == 0){
      float ci = sigm(s1+dg.y)*c + sigm(s0+dg.x)*tanh_f(s2+dg.z);
      c = ci;
      float h = sigm(s3+dg.w)*tanh_f(ci);
      Yh[step*576 + u] = h;
      __hip_atomic_store(yout + u, h, __ATOMIC_RELAXED, __HIP_MEMORY_SCOPE_AGENT);
    }
    __syncthreads();
    if (tid == 0){
      __hip_atomic_fetch_add(cnt, 1, __ATOMIC_ACQ_REL, __HIP_MEMORY_SCOPE_AGENT);
      const int target = DEC_NWG*(step+1);
      while (__hip_atomic_load(cnt, __ATOMIC_ACQUIRE, __HIP_MEMORY_SCOPE_AGENT) < target)
        __builtin_amdgcn_s_sleep(1);
    }
    __syncthreads();
  }
}

// ---------------- out[t][m] = lin_b[m] + lin_w[m] . y_t ----------------
__global__ __launch_bounds__(256) void k_final(const float* __restrict__ Yh, const float* __restrict__ lw,
                        const float* __restrict__ lb, float* __restrict__ out){
  __shared__ float ys[514];
  int t = blockIdx.x, tid = threadIdx.x;
  for (int i=tid;i<514;i+=256) ys[i] = Yh[t*576+i];
  __syncthreads();
  for (int m=tid; m<257; m+=256){
    float s = lb[m];
    const float* wr = lw + (size_t)m*514;
    for (int k=0;k<514;k++) s += wr[k]*ys[k];
    out[t*257+m] = s;
  }
}

extern "C" void kernel_launch(void* const* d_in, const int* in_sizes, int n_in,
                              void* d_out, int out_size, void* d_ws, size_t ws_size,
                              hipStream_t stream){
  const float* src  = (const float*)d_in[0];
  const float* c1w = (const float*)d_in[1];  const float* c1b = (const float*)d_in[2];
  const float* c2w = (const float*)d_in[3];  const float* c2b = (const float*)d_in[4];
  const float* c3w = (const float*)d_in[5];  const float* c3b = (const float*)d_in[6];
  const float* c4w = (const float*)d_in[7];  const float* c4b = (const float*)d_in[8];
  const float* c5w = (const float*)d_in[9];  const float* c5b = (const float*)d_in[10];
  const float* c6w = (const float*)d_in[11]; const float* c6b = (const float*)d_in[12];
  const float* fc1w= (const float*)d_in[13]; const float* fc1b= (const float*)d_in[14];
  const float* fc2w= (const float*)d_in[15]; const float* fc2b= (const float*)d_in[16];
  const float* fc3w= (const float*)d_in[17]; const float* fc3b= (const float*)d_in[18];
  const float* ewihf=(const float*)d_in[19];
  const float* ebihf=(const float*)d_in[21]; const float* ebhhf=(const float*)d_in[22];
  const float* ewihb=(const float*)d_in[23];
  const float* ebihb=(const float*)d_in[25]; const float* ebhhb=(const float*)d_in[26];
  const float* dwihf=(const float*)d_in[27]; const float* dwhhf=(const float*)d_in[28];
  const float* dbihf=(const float*)d_in[29]; const float* dbhhf=(const float*)d_in[30];
  const float* dwihb=(const float*)d_in[31]; const float* dwhhb=(const float*)d_in[32];
  const float* dbihb=(const float*)d_in[33]; const float* dbhhb=(const float*)d_in[34];
  const float* lw  = (const float*)d_in[35]; const float* lbv = (const float*)d_in[36];
  float* out = (float*)d_out;

  float* W = (float*)d_ws;
  // float offsets
  float* cnt_f = W + 0;          // int counter lives here
  float* ybuf  = W + 64;         // 2 x 576
  float* cinit = W + 1216;       // 528
  float* gates = W + 1744;       // 2056
  float* dv    = W + 3840;       // 2112
  float* A     = W + 5952;       // 528*4*576 = 1216512
  float* C     = W + 1222464;    // 2056*514 = 1056784
  float* Yh    = W + 2279296;    // 128*576
  float* part  = W + 2353024;    // up to 1179648
  float* X0    = W + 3532672;    // 294912
  float* X1    = W + 3827584;    // 247808
  float* xfc   = W + 4075392;    // 51200
  float* f1    = W + 4126592;    // 2048
  float* f2    = W + 4128640;    // 512
  float* feat  = W + 4129152;    // 128

  // setup (zeros ybuf + cinit contiguously, 1680 floats, and counter)
  k_setup<<<1,256,0,stream>>>(ybuf, 1152+528, (int*)cnt_f);

  // decoder fused-weight precompute
  k_gemm_wl<<<33*9,256,0,stream>>>(dwihf, dwihb, lw, C);
  k_assemble<<<DIV_UP(528*4*576,256),256,0,stream>>>(C, dwhhf, dwhhb, A);
  k_dvec<<<DIV_UP(2112,256),256,0,stream>>>(dwihf, dwihb, dbihf, dbhhf, dbihb, dbhhb, lbv, dv);

  // CNN chain
  k_pool1<<<128,256,0,stream>>>(src, X0);
  k_conv_gemm<3><<<1*15*18,256,0,stream>>>(X0, c1w, part, 32,32,32,  64,30,30, 18, 16);
  k_conv_reduce<<<DIV_UP(64*900,256),256,0,stream>>>(part, c1b, X1, 64, 900, 18);
  k_conv_gemm<3><<<2*13*9,256,0,stream>>>(X1, c2w, part, 64,30,30, 128,28,28, 9, 64);
  k_conv_reduce<<<DIV_UP(128*784,256),256,0,stream>>>(part, c2b, X0, 128, 784, 9);
  k_conv_gemm<3><<<4*11*6,256,0,stream>>>(X0, c3w, part, 128,28,28, 256,26,26, 6, 192);
  k_conv_reduce<<<DIV_UP(256*676,256),256,0,stream>>>(part, c3b, X1, 256, 676, 6);
  k_conv_gemm<3><<<8*9*4,256,0,stream>>>(X1, c4w, part, 256,26,26, 512,24,24, 4, 576);
  k_conv_reduce<<<DIV_UP(512*576,256),256,0,stream>>>(part, c4b, X0, 512, 576, 4);
  k_conv_gemm<3><<<8*8*4,256,0,stream>>>(X0, c5w, part, 512,24,24, 512,22,22, 4, 1152);
  k_conv_reduce<<<DIV_UP(512*484,256),256,0,stream>>>(part, c5b, X1, 512, 484, 4);
  k_conv_gemm<2><<<8*7*4,256,0,stream>>>(X1, c6w, part, 512,22,22, 512,21,21, 4, 512);
  k_conv_reduce<<<DIV_UP(512*441,256),256,0,stream>>>(part, c6b, X0, 512, 441, 4);
  k_pool2<<<200,256,0,stream>>>(X0, xfc);

  // FC stack
  k_fc<<<2048,256,0,stream>>>(fc1w, xfc, fc1b, f1, 51200, 1);
  k_fc<<<512,256,0,stream>>>(fc2w, f1, fc2b, f2, 2048, 1);
  k_fc<<<128,256,0,stream>>>(fc3w, f2, fc3b, feat, 512, 0);

  // encoder (zero initial state => whh term drops)
  k_enc_gates<<<9,256,0,stream>>>(ewihf, ewihb, ebihf, ebhhf, ebihb, ebhhb, feat, gates);
  k_enc_point<<<3,256,0,stream>>>(gates, ybuf, cinit);

  // persistent decoder: 128 steps, one device-wide barrier per step
  k_decode<<<DEC_NWG,256,0,stream>>>(A, dv, cinit, ybuf, Yh, (int*)cnt_f);

  // output projection
  k_final<<<128,256,0,stream>>>(Yh, lw, lbv, out);
}

// Round 2
// 1565.118 us; speedup vs baseline: 1.1181x; 1.1181x over previous
//
#include <hip/hip_runtime.h>

#define DIV_UP(a,b) (((a)+(b)-1)/(b))
#define DEC_NWG 33
#define POISON 0xAAAAAAAAu

__device__ __forceinline__ float sigm(float x){ return 1.f/(1.f+__expf(-x)); }
__device__ __forceinline__ float tanh_f(float x){ return 1.f - 2.f/(__expf(2.f*x)+1.f); }

__device__ __forceinline__ void fma4x4(const float4 wv, const float4 xv, float acc[4][4]){
  acc[0][0] += wv.x*xv.x; acc[0][1] += wv.x*xv.y; acc[0][2] += wv.x*xv.z; acc[0][3] += wv.x*xv.w;
  acc[1][0] += wv.y*xv.x; acc[1][1] += wv.y*xv.y; acc[1][2] += wv.y*xv.z; acc[1][3] += wv.y*xv.w;
  acc[2][0] += wv.z*xv.x; acc[2][1] += wv.z*xv.y; acc[2][2] += wv.z*xv.z; acc[2][3] += wv.z*xv.w;
  acc[3][0] += wv.w*xv.x; acc[3][1] += wv.w*xv.y; acc[3][2] += wv.w*xv.z; acc[3][3] += wv.w*xv.w;
}

// ---------------- setup: poison Ydec rows 1..128 (don't rely on harness poison) ----------------
__global__ void k_setup(unsigned int* ydec){
  int idx = blockIdx.x*256 + threadIdx.x;   // 128*576 = 73728
  if (idx < 128*576) ydec[576 + idx] = POISON;
}

// ---------------- pool1: 4x4/4 maxpool (32,128,128)->(32,32,32) ----------------
__global__ void k_pool1(const float* __restrict__ src, float* __restrict__ out){
  int idx = blockIdx.x*256 + threadIdx.x;
  if (idx >= 32*32*32) return;
  int x = idx & 31, y = (idx>>5)&31, c = idx>>10;
  const float* p = src + ((size_t)(c*128) + y*4)*128 + x*4;
  float m = -1e30f;
  #pragma unroll
  for (int i=0;i<4;i++)
    #pragma unroll
    for (int j=0;j<4;j++) m = fmaxf(m, p[i*128+j]);
  out[idx] = m;
}

// ---------------- conv as im2col-GEMM, 64oc x 64px tile, K-split G ----------------
template<int KS>
__global__ __launch_bounds__(256) void k_conv_gemm(
    const float* __restrict__ in, const float* __restrict__ w,
    float* __restrict__ part,
    int Cin, int Hin, int Win, int Cout, int Hout, int Wout, int G, int kchunk)
{
  const int P = Hout*Wout;
  const int K = Cin*KS*KS;
  const int pxT = (P+63)>>6;
  int b = blockIdx.x;
  const int g = b % G; b /= G;
  const int pt = b % pxT; const int ot = b / pxT;
  const int k0 = g*kchunk;
  const int k1 = min(K, k0+kchunk);
  const int tid = threadIdx.x;
  const int tx = tid & 15, ty = tid >> 4;
  const int sp = tid & 63, sk = tid >> 6;
  int p_st = pt*64 + sp;
  bool pv = p_st < P;
  int pys = 0, pxs = 0;
  if (pv){ pys = p_st / Wout; pxs = p_st - pys*Wout; }
  __shared__ __align__(16) float Xs[16][64];
  __shared__ __align__(16) float Ws[16][68];
  float acc[4][4];
  #pragma unroll
  for (int i=0;i<4;i++)
    #pragma unroll
    for (int j=0;j<4;j++) acc[i][j]=0.f;
  for (int kb=k0; kb<k1; kb+=16){
    #pragma unroll
    for (int i=0;i<4;i++){
      int k = kb + sk + i*4;
      float v = 0.f;
      if (k < k1 && pv){
        int ic = k/(KS*KS); int t = k - ic*(KS*KS); int ky = t/KS, kx = t - ky*KS;
        v = in[((size_t)(ic*Hin) + pys+ky)*Win + (pxs+kx)];
      }
      Xs[sk+i*4][sp] = v;
    }
    #pragma unroll
    for (int i=0;i<4;i++){
      int k = kb + tx;
      int oc = ot*64 + ty + i*16;
      Ws[tx][ty+i*16] = (k < k1) ? w[(size_t)oc*K + k] : 0.f;
    }
    __syncthreads();
    #pragma unroll
    for (int kk=0;kk<16;kk++){
      float4 wv = *(const float4*)&Ws[kk][ty*4];
      float4 xv = *(const float4*)&Xs[kk][tx*4];
      fma4x4(wv, xv, acc);
    }
    __syncthreads();
  }
  float* po = part + (size_t)g*Cout*P;
  #pragma unroll
  for (int i=0;i<4;i++){
    int oc = ot*64 + ty*4 + i;
    #pragma unroll
    for (int j=0;j<4;j++){
      int p = pt*64 + tx*4 + j;
      if (p < P) po[(size_t)oc*P + p] = acc[i][j];
    }
  }
}

__global__ void k_conv_reduce(const float* __restrict__ part, const float* __restrict__ bias,
                              float* __restrict__ out, int Cout, int P, int G){
  int idx = blockIdx.x*256 + threadIdx.x;
  int total = Cout*P;
  if (idx >= total) return;
  int oc = idx / P;
  float s = bias[oc];
  for (int g=0; g<G; g++) s += part[(size_t)g*total + idx];
  out[idx] = fmaxf(s, 0.f);
}

// ---------------- pool2: 3x3/2 maxpool (512,21,21)->(512,10,10) flat ----------------
__global__ void k_pool2(const float* __restrict__ in, float* __restrict__ out){
  int idx = blockIdx.x*256 + threadIdx.x;
  if (idx >= 51200) return;
  int x = idx % 10; int y = (idx/10)%10; int c = idx/100;
  const float* p = in + ((size_t)(c*21) + y*2)*21 + x*2;
  float m = -1e30f;
  #pragma unroll
  for (int i=0;i<3;i++)
    #pragma unroll
    for (int j=0;j<3;j++) m = fmaxf(m, p[i*21+j]);
  out[idx] = m;
}

// ---------------- fc matvec: one row per block ----------------
__global__ __launch_bounds__(256) void k_fc(const float* __restrict__ w, const float* __restrict__ x,
                     const float* __restrict__ b, float* __restrict__ out, int N, int do_relu){
  int row = blockIdx.x;
  int tid = threadIdx.x;
  const float* wr = w + (size_t)row*N;
  float s = 0.f;
  for (int i = tid*4; i < N; i += 1024){
    float4 wv = *(const float4*)(wr + i);
    float4 xv = *(const float4*)(x + i);
    s += wv.x*xv.x + wv.y*xv.y + wv.z*xv.z + wv.w*xv.w;
  }
  #pragma unroll
  for (int off=32; off; off>>=1) s += __shfl_xor(s, off, 64);
  __shared__ float red[4];
  if ((tid & 63) == 0) red[tid>>6] = s;
  __syncthreads();
  if (tid == 0){
    float t = red[0]+red[1]+red[2]+red[3] + b[row];
    if (do_relu) t = fmaxf(t, 0.f);
    out[row] = t;
  }
}

// ---------------- C = [dec_wih_f; dec_wih_b](2056x257) @ lin_w(257x514) ----------------
__global__ __launch_bounds__(256) void k_gemm_wl(
    const float* __restrict__ wf, const float* __restrict__ wb,
    const float* __restrict__ lw, float* __restrict__ C)
{
  int b = blockIdx.x;
  int nt = b % 9; int mt = b / 9;   // 33 x 9 tiles
  int tid = threadIdx.x;
  int tx = tid&15, ty = tid>>4;
  int sp = tid&63, sk = tid>>6;
  __shared__ __align__(16) float Xs[16][64];
  __shared__ __align__(16) float Ws[16][68];
  float acc[4][4];
  #pragma unroll
  for (int i=0;i<4;i++)
    #pragma unroll
    for (int j=0;j<4;j++) acc[i][j]=0.f;
  for (int kb=0; kb<257; kb+=16){
    #pragma unroll
    for (int i=0;i<4;i++){
      int k = kb+sk+i*4;
      int col = nt*64 + sp;
      Xs[sk+i*4][sp] = (k<257 && col<514) ? lw[(size_t)k*514+col] : 0.f;
    }
    #pragma unroll
    for (int i=0;i<4;i++){
      int k = kb+tx;
      int row = mt*64 + ty + i*16;
      float v = 0.f;
      if (k<257 && row<2056)
        v = (row<1028) ? wf[(size_t)row*257+k] : wb[(size_t)(row-1028)*257+k];
      Ws[tx][ty+i*16] = v;
    }
    __syncthreads();
    #pragma unroll
    for (int kk=0;kk<16;kk++){
      float4 wv = *(const float4*)&Ws[kk][ty*4];
      float4 xv = *(const float4*)&Xs[kk][tx*4];
      fma4x4(wv, xv, acc);
    }
    __syncthreads();
  }
  #pragma unroll
  for (int i=0;i<4;i++){
    int row = mt*64 + ty*4 + i;
    #pragma unroll
    for (int j=0;j<4;j++){
      int col = nt*64 + tx*4 + j;
      if (row<2056 && col<514) C[(size_t)row*514+col] = acc[i][j];
    }
  }
}

// ---------------- assemble A[u][g][576] = C + Whh block (zero-padded) ----------------
__global__ void k_assemble(const float* __restrict__ C, const float* __restrict__ whf,
                           const float* __restrict__ whb, float* __restrict__ A){
  int idx = blockIdx.x*256+threadIdx.x;
  if (idx >= 528*4*576) return;
  int k = idx % 576;
  int g = (idx/576)&3;
  int u = idx/2304;
  float v = 0.f;
  if (u < 514 && k < 514){
    int j = (u<257)? u : u-257;
    int row = ((u<257)?0:1028) + g*257 + j;
    v = C[(size_t)row*514 + k];
    if (u<257){ if (k<257) v += whf[(size_t)(g*257+j)*257 + k]; }
    else      { if (k>=257) v += whb[(size_t)(g*257+j)*257 + (k-257)]; }
  }
  A[idx] = v;
}

// ---------------- d[u][g] = wih_row . lin_b + bih + bhh (wave per row) ----------------
__global__ void k_dvec(const float* __restrict__ wihf, const float* __restrict__ wihb,
                       const float* __restrict__ bihf, const float* __restrict__ bhhf,
                       const float* __restrict__ bihb, const float* __restrict__ bhhb,
                       const float* __restrict__ lb, float* __restrict__ dv){
  int row = blockIdx.x*4 + (threadIdx.x>>6);   // row = u*4+g, 2112 rows
  if (row >= 528*4) return;
  int u = row>>2, g = row&3;
  int lane = threadIdx.x & 63;
  float s = 0.f;
  float v = 0.f;
  if (u < 514){
    int j = (u<257)? u : u-257;
    int r = g*257+j;
    const float* wr = ((u<257)? wihf : wihb) + (size_t)r*257;
    for (int m=lane;m<257;m+=64) s += wr[m]*lb[m];
    #pragma unroll
    for (int off=32; off; off>>=1) s += __shfl_xor(s, off, 64);
    v = s + ((u<257) ? (bihf[r]+bhhf[r]) : (bihb[r]+bhhb[r]));
  }
  if (lane == 0) dv[row] = v;
}

// ---------------- encoder (h0=c0=0 so whh term vanishes) ----------------
__global__ void k_enc_gates(const float* __restrict__ wf, const float* __restrict__ wb,
                            const float* __restrict__ bihf, const float* __restrict__ bhhf,
                            const float* __restrict__ bihb, const float* __restrict__ bhhb,
                            const float* __restrict__ feat, float* __restrict__ gates){
  __shared__ float fs[128];
  int tid = threadIdx.x;
  if (tid < 128) fs[tid] = feat[tid];
  __syncthreads();
  int r = blockIdx.x*256 + tid;
  if (r >= 2056) return;
  const float* wr; float bias;
  if (r < 1028){ wr = wf + (size_t)r*128; bias = bihf[r]+bhhf[r]; }
  else { int rr = r-1028; wr = wb + (size_t)rr*128; bias = bihb[rr]+bhhb[rr]; }
  float s = bias;
  for (int m=0;m<128;m++) s += wr[m]*fs[m];
  gates[r] = s;
}

// writes Ydec row 0 (528 entries: 514 real + 14 zeros) and cinit (528)
__global__ void k_enc_point(const float* __restrict__ gates, float* __restrict__ ydec0,
                            float* __restrict__ cinit){
  int u = blockIdx.x*256+threadIdx.x;
  if (u >= 528) return;
  float h = 0.f, c = 0.f;
  if (u < 514){
    int j = (u<257)? u : u-257;
    int base = (u<257)? 0 : 1028;
    float gi = gates[base + j];
    float gg = gates[base + 514 + j];
    float go = gates[base + 771 + j];
    c = sigm(gi)*tanh_f(gg);
    h = sigm(go)*tanh_f(c);
  }
  ydec0[u] = h; cinit[u] = c;
}

// ---------------- persistent fused decoder: data-flow sync via poison polling ----------------
__global__ __launch_bounds__(256,1) void k_decode(
    const float* __restrict__ A, const float* __restrict__ dv,
    const float* __restrict__ cinit, float* __restrict__ Ydec)
{
  const int tid = threadIdx.x;
  const int u = blockIdx.x*16 + (tid>>4);
  const int q = tid & 15;
  float w[4][36];
  {
    const float* base = A + (size_t)u*4*576 + q*36;
    #pragma unroll
    for (int g=0; g<4; g++){
      #pragma unroll
      for (int i=0;i<36;i+=4){
        float4 v = *(const float4*)(base + g*576 + i);
        w[g][i]=v.x; w[g][i+1]=v.y; w[g][i+2]=v.z; w[g][i+3]=v.w;
      }
    }
  }
  const float4 dg = *(const float4*)(dv + u*4);
  float c = cinit[u];
  __shared__ __align__(16) float ys[2][576];
  for (int step=0; step<128; step++){
    float* ysb = ys[step&1];
    if (tid < 64){
      // wave 0 polls row `step` directly on the data (poison pattern = not yet written)
      const unsigned int* rowp = (const unsigned int*)(Ydec + (size_t)step*576);
      unsigned int v[9];
      while (true){
        bool ok = true;
        #pragma unroll
        for (int j=0;j<9;j++){
          int idx = tid + j*64;
          v[j] = __hip_atomic_load(rowp + idx, __ATOMIC_RELAXED, __HIP_MEMORY_SCOPE_AGENT);
          if (idx < 528 && v[j] == POISON) ok = false;
        }
        if (__all(ok)) break;
      }
      #pragma unroll
      for (int j=0;j<9;j++){
        int idx = tid + j*64;
        ((unsigned int*)ysb)[idx] = (idx < 528) ? v[j] : 0u;
      }
    }
    __syncthreads();
    float s0=0.f, s1=0.f, s2=0.f, s3=0.f;
    const float4* yl4 = (const float4*)&ysb[q*36];
    #pragma unroll
    for (int i=0;i<9;i++){
      float4 yv = yl4[i];
      s0 += w[0][i*4]*yv.x + w[0][i*4+1]*yv.y + w[0][i*4+2]*yv.z + w[0][i*4+3]*yv.w;
      s1 += w[1][i*4]*yv.x + w[1][i*4+1]*yv.y + w[1][i*4+2]*yv.z + w[1][i*4+3]*yv.w;
      s2 += w[2][i*4]*yv.x + w[2][i*4+1]*yv.y + w[2][i*4+2]*yv.z + w[2][i*4+3]*yv.w;
      s3 += w[3][i*4]*yv.x + w[3][i*4+1]*yv.y + w[3][i*4+2]*yv.z + w[3][i*4+3]*yv.w;
    }
    #pragma unroll
    for (int off=8; off; off>>=1){
      s0 += __shfl_xor(s0, off, 64);
      s1 += __shfl_xor(s1, off, 64);
      s2 += __shfl_xor(s2, off, 64);
      s3 += __shfl_xor(s3, off, 64);
    }
    if (q == 0){
      float ci = sigm(s1+dg.y)*c + sigm(s0+dg.x)*tanh_f(s2+dg.z);
      c = ci;
      float h = sigm(s3+dg.w)*tanh_f(ci);
      __hip_atomic_store(Ydec + (size_t)(step+1)*576 + u, h,
                         __ATOMIC_RELAXED, __HIP_MEMORY_SCOPE_AGENT);
    }
    // no second barrier needed: next poll writes the other LDS buffer
  }
}

// ---------------- out[t][m] = lin_b[m] + lin_w[m] . y_{t+1} ----------------
__global__ __launch_bounds__(256) void k_final(const float* __restrict__ Ydec, const float* __restrict__ lw,
                        const float* __restrict__ lb, float* __restrict__ out){
  __shared__ float ysl[514];
  int t = blockIdx.x, tid = threadIdx.x;
  for (int i=tid;i<514;i+=256) ysl[i] = Ydec[(size_t)(t+1)*576+i];
  __syncthreads();
  for (int m=tid; m<257; m+=256){
    float s = lb[m];
    const float* wr = lw + (size_t)m*514;
    for (int k=0;k<514;k++) s += wr[k]*ysl[k];
    out[t*257+m] = s;
  }
}

extern "C" void kernel_launch(void* const* d_in, const int* in_sizes, int n_in,
                              void* d_out, int out_size, void* d_ws, size_t ws_size,
                              hipStream_t stream){
  const float* src  = (const float*)d_in[0];
  const float* c1w = (const float*)d_in[1];  const float* c1b = (const float*)d_in[2];
  const float* c2w = (const float*)d_in[3];  const float* c2b = (const float*)d_in[4];
  const float* c3w = (const float*)d_in[5];  const float* c3b = (const float*)d_in[6];
  const float* c4w = (const float*)d_in[7];  const float* c4b = (const float*)d_in[8];
  const float* c5w = (const float*)d_in[9];  const float* c5b = (const float*)d_in[10];
  const float* c6w = (const float*)d_in[11]; const float* c6b = (const float*)d_in[12];
  const float* fc1w= (const float*)d_in[13]; const float* fc1b= (const float*)d_in[14];
  const float* fc2w= (const float*)d_in[15]; const float* fc2b= (const float*)d_in[16];
  const float* fc3w= (const float*)d_in[17]; const float* fc3b= (const float*)d_in[18];
  const float* ewihf=(const float*)d_in[19];
  const float* ebihf=(const float*)d_in[21]; const float* ebhhf=(const float*)d_in[22];
  const float* ewihb=(const float*)d_in[23];
  const float* ebihb=(const float*)d_in[25]; const float* ebhhb=(const float*)d_in[26];
  const float* dwihf=(const float*)d_in[27]; const float* dwhhf=(const float*)d_in[28];
  const float* dbihf=(const float*)d_in[29]; const float* dbhhf=(const float*)d_in[30];
  const float* dwihb=(const float*)d_in[31]; const float* dwhhb=(const float*)d_in[32];
  const float* dbihb=(const float*)d_in[33]; const float* dbhhb=(const float*)d_in[34];
  const float* lw  = (const float*)d_in[35]; const float* lbv = (const float*)d_in[36];
  float* out = (float*)d_out;

  float* W = (float*)d_ws;
  float* cinit = W + 0;          // 528
  float* gates = W + 528;        // 2056
  float* dv    = W + 2584;       // 2112
  float* A     = W + 4704;       // 528*4*576 = 1216512
  float* C     = W + 1221216;    // 2056*514 = 1056784
  float* Ydec  = W + 2278000;    // 129*576 = 74304
  float* part  = W + 2352304;    // up to 1179648
  float* X0    = W + 3531952;    // 294912
  float* X1    = W + 3826864;    // 247808
  float* xfc   = W + 4074672;    // 51200
  float* f1    = W + 4125872;    // 2048
  float* f2    = W + 4127920;    // 512
  float* feat  = W + 4128432;    // 128

  // poison Ydec rows 1..128 (decode's data-flow sync polls against this)
  k_setup<<<288,256,0,stream>>>((unsigned int*)Ydec);

  // decoder fused-weight precompute
  k_gemm_wl<<<33*9,256,0,stream>>>(dwihf, dwihb, lw, C);
  k_assemble<<<DIV_UP(528*4*576,256),256,0,stream>>>(C, dwhhf, dwhhb, A);
  k_dvec<<<528,256,0,stream>>>(dwihf, dwihb, dbihf, dbhhf, dbihb, dbhhb, lbv, dv);

  // CNN chain
  k_pool1<<<128,256,0,stream>>>(src, X0);
  k_conv_gemm<3><<<1*15*18,256,0,stream>>>(X0, c1w, part, 32,32,32,  64,30,30, 18, 16);
  k_conv_reduce<<<DIV_UP(64*900,256),256,0,stream>>>(part, c1b, X1, 64, 900, 18);
  k_conv_gemm<3><<<2*13*9,256,0,stream>>>(X1, c2w, part, 64,30,30, 128,28,28, 9, 64);
  k_conv_reduce<<<DIV_UP(128*784,256),256,0,stream>>>(part, c2b, X0, 128, 784, 9);
  k_conv_gemm<3><<<4*11*6,256,0,stream>>>(X0, c3w, part, 128,28,28, 256,26,26, 6, 192);
  k_conv_reduce<<<DIV_UP(256*676,256),256,0,stream>>>(part, c3b, X1, 256, 676, 6);
  k_conv_gemm<3><<<8*9*4,256,0,stream>>>(X1, c4w, part, 256,26,26, 512,24,24, 4, 576);
  k_conv_reduce<<<DIV_UP(512*576,256),256,0,stream>>>(part, c4b, X0, 512, 576, 4);
  k_conv_gemm<3><<<8*8*4,256,0,stream>>>(X0, c5w, part, 512,24,24, 512,22,22, 4, 1152);
  k_conv_reduce<<<DIV_UP(512*484,256),256,0,stream>>>(part, c5b, X1, 512, 484, 4);
  k_conv_gemm<2><<<8*7*4,256,0,stream>>>(X1, c6w, part, 512,22,22, 512,21,21, 4, 512);
  k_conv_reduce<<<DIV_UP(512*441,256),256,0,stream>>>(part, c6b, X0, 512, 441, 4);
  k_pool2<<<200,256,0,stream>>>(X0, xfc);

  // FC stack
  k_fc<<<2048,256,0,stream>>>(fc1w, xfc, fc1b, f1, 51200, 1);
  k_fc<<<512,256,0,stream>>>(fc2w, f1, fc2b, f2, 2048, 1);
  k_fc<<<128,256,0,stream>>>(fc3w, f2, fc3b, feat, 512, 0);

  // encoder (zero initial state => whh term drops)
  k_enc_gates<<<9,256,0,stream>>>(ewihf, ewihb, ebihf, ebhhf, ebihb, ebhhb, feat, gates);
  k_enc_point<<<3,256,0,stream>>>(gates, Ydec, cinit);

  // persistent decoder: 128 steps, data-flow sync (no counter, no sleep)
  k_decode<<<DEC_NWG,256,0,stream>>>(A, dv, cinit, Ydec);

  // output projection
  k_final<<<128,256,0,stream>>>(Ydec, lw, lbv, out);
}

// Round 3
// 1517.567 us; speedup vs baseline: 1.1531x; 1.0313x over previous
//
#include <hip/hip_runtime.h>

#define DIV_UP(a,b) (((a)+(b)-1)/(b))
#define DEC_NWG 33
#define POISON 0xAAAAAAAAu

__device__ __forceinline__ float sigm(float x){ return 1.f/(1.f+__expf(-x)); }
__device__ __forceinline__ float tanh_f(float x){ return 1.f - 2.f/(__expf(2.f*x)+1.f); }

__device__ __forceinline__ void fma4x4(const float4 wv, const float4 xv, float acc[4][4]){
  acc[0][0] += wv.x*xv.x; acc[0][1] += wv.x*xv.y; acc[0][2] += wv.x*xv.z; acc[0][3] += wv.x*xv.w;
  acc[1][0] += wv.y*xv.x; acc[1][1] += wv.y*xv.y; acc[1][2] += wv.y*xv.z; acc[1][3] += wv.y*xv.w;
  acc[2][0] += wv.z*xv.x; acc[2][1] += wv.z*xv.y; acc[2][2] += wv.z*xv.z; acc[2][3] += wv.z*xv.w;
  acc[3][0] += wv.w*xv.x; acc[3][1] += wv.w*xv.y; acc[3][2] += wv.w*xv.z; acc[3][3] += wv.w*xv.w;
}

// ---------------- setup: poison Ydec rows 1..128 ----------------
__global__ void k_setup(unsigned int* ydec){
  int idx = blockIdx.x*256 + threadIdx.x;   // 128*576 = 73728
  if (idx < 128*576) ydec[576 + idx] = POISON;
}

// ---------------- pool1: 4x4/4 maxpool (32,128,128)->(32,32,32) ----------------
__global__ void k_pool1(const float* __restrict__ src, float* __restrict__ out){
  int idx = blockIdx.x*256 + threadIdx.x;
  if (idx >= 32*32*32) return;
  int x = idx & 31, y = (idx>>5)&31, c = idx>>10;
  const float* p = src + ((size_t)(c*128) + y*4)*128 + x*4;
  float m = -1e30f;
  #pragma unroll
  for (int i=0;i<4;i++)
    #pragma unroll
    for (int j=0;j<4;j++) m = fmaxf(m, p[i*128+j]);
  out[idx] = m;
}

// ---------------- conv as im2col-GEMM, 64oc x 64px tile, K-split G ----------------
template<int KS>
__global__ __launch_bounds__(256) void k_conv_gemm(
    const float* __restrict__ in, const float* __restrict__ w,
    float* __restrict__ part,
    int Cin, int Hin, int Win, int Cout, int Hout, int Wout, int G, int kchunk)
{
  const int P = Hout*Wout;
  const int K = Cin*KS*KS;
  const int pxT = (P+63)>>6;
  int b = blockIdx.x;
  const int g = b % G; b /= G;
  const int pt = b % pxT; const int ot = b / pxT;
  const int k0 = g*kchunk;
  const int k1 = min(K, k0+kchunk);
  const int tid = threadIdx.x;
  const int tx = tid & 15, ty = tid >> 4;
  const int sp = tid & 63, sk = tid >> 6;
  int p_st = pt*64 + sp;
  bool pv = p_st < P;
  int pys = 0, pxs = 0;
  if (pv){ pys = p_st / Wout; pxs = p_st - pys*Wout; }
  __shared__ __align__(16) float Xs[16][64];
  __shared__ __align__(16) float Ws[16][68];
  float acc[4][4];
  #pragma unroll
  for (int i=0;i<4;i++)
    #pragma unroll
    for (int j=0;j<4;j++) acc[i][j]=0.f;
  for (int kb=k0; kb<k1; kb+=16){
    #pragma unroll
    for (int i=0;i<4;i++){
      int k = kb + sk + i*4;
      float v = 0.f;
      if (k < k1 && pv){
        int ic = k/(KS*KS); int t = k - ic*(KS*KS); int ky = t/KS, kx = t - ky*KS;
        v = in[((size_t)(ic*Hin) + pys+ky)*Win + (pxs+kx)];
      }
      Xs[sk+i*4][sp] = v;
    }
    #pragma unroll
    for (int i=0;i<4;i++){
      int k = kb + tx;
      int oc = ot*64 + ty + i*16;
      Ws[tx][ty+i*16] = (k < k1) ? w[(size_t)oc*K + k] : 0.f;
    }
    __syncthreads();
    #pragma unroll
    for (int kk=0;kk<16;kk++){
      float4 wv = *(const float4*)&Ws[kk][ty*4];
      float4 xv = *(const float4*)&Xs[kk][tx*4];
      fma4x4(wv, xv, acc);
    }
    __syncthreads();
  }
  float* po = part + (size_t)g*Cout*P;
  #pragma unroll
  for (int i=0;i<4;i++){
    int oc = ot*64 + ty*4 + i;
    #pragma unroll
    for (int j=0;j<4;j++){
      int p = pt*64 + tx*4 + j;
      if (p < P) po[(size_t)oc*P + p] = acc[i][j];
    }
  }
}

__global__ void k_conv_reduce(const float* __restrict__ part, const float* __restrict__ bias,
                              float* __restrict__ out, int Cout, int P, int G){
  int idx = blockIdx.x*256 + threadIdx.x;
  int total = Cout*P;
  if (idx >= total) return;
  int oc = idx / P;
  float s = bias[oc];
  for (int g=0; g<G; g++) s += part[(size_t)g*total + idx];
  out[idx] = fmaxf(s, 0.f);
}

// ---------------- pool2: 3x3/2 maxpool (512,21,21)->(512,10,10) flat ----------------
__global__ void k_pool2(const float* __restrict__ in, float* __restrict__ out){
  int idx = blockIdx.x*256 + threadIdx.x;
  if (idx >= 51200) return;
  int x = idx % 10; int y = (idx/10)%10; int c = idx/100;
  const float* p = in + ((size_t)(c*21) + y*2)*21 + x*2;
  float m = -1e30f;
  #pragma unroll
  for (int i=0;i<3;i++)
    #pragma unroll
    for (int j=0;j<3;j++) m = fmaxf(m, p[i*21+j]);
  out[idx] = m;
}

// ---------------- fc matvec: one row per block ----------------
__global__ __launch_bounds__(256) void k_fc(const float* __restrict__ w, const float* __restrict__ x,
                     const float* __restrict__ b, float* __restrict__ out, int N, int do_relu){
  int row = blockIdx.x;
  int tid = threadIdx.x;
  const float* wr = w + (size_t)row*N;
  float s = 0.f;
  for (int i = tid*4; i < N; i += 1024){
    float4 wv = *(const float4*)(wr + i);
    float4 xv = *(const float4*)(x + i);
    s += wv.x*xv.x + wv.y*xv.y + wv.z*xv.z + wv.w*xv.w;
  }
  #pragma unroll
  for (int off=32; off; off>>=1) s += __shfl_xor(s, off, 64);
  __shared__ float red[4];
  if ((tid & 63) == 0) red[tid>>6] = s;
  __syncthreads();
  if (tid == 0){
    float t = red[0]+red[1]+red[2]+red[3] + b[row];
    if (do_relu) t = fmaxf(t, 0.f);
    out[row] = t;
  }
}

// ---------------- C = [dec_wih_f; dec_wih_b](2056x257) @ lin_w(257x514) ----------------
__global__ __launch_bounds__(256) void k_gemm_wl(
    const float* __restrict__ wf, const float* __restrict__ wb,
    const float* __restrict__ lw, float* __restrict__ C)
{
  int b = blockIdx.x;
  int nt = b % 9; int mt = b / 9;   // 33 x 9 tiles
  int tid = threadIdx.x;
  int tx = tid&15, ty = tid>>4;
  int sp = tid&63, sk = tid>>6;
  __shared__ __align__(16) float Xs[16][64];
  __shared__ __align__(16) float Ws[16][68];
  float acc[4][4];
  #pragma unroll
  for (int i=0;i<4;i++)
    #pragma unroll
    for (int j=0;j<4;j++) acc[i][j]=0.f;
  for (int kb=0; kb<257; kb+=16){
    #pragma unroll
    for (int i=0;i<4;i++){
      int k = kb+sk+i*4;
      int col = nt*64 + sp;
      Xs[sk+i*4][sp] = (k<257 && col<514) ? lw[(size_t)k*514+col] : 0.f;
    }
    #pragma unroll
    for (int i=0;i<4;i++){
      int k = kb+tx;
      int row = mt*64 + ty + i*16;
      float v = 0.f;
      if (k<257 && row<2056)
        v = (row<1028) ? wf[(size_t)row*257+k] : wb[(size_t)(row-1028)*257+k];
      Ws[tx][ty+i*16] = v;
    }
    __syncthreads();
    #pragma unroll
    for (int kk=0;kk<16;kk++){
      float4 wv = *(const float4*)&Ws[kk][ty*4];
      float4 xv = *(const float4*)&Xs[kk][tx*4];
      fma4x4(wv, xv, acc);
    }
    __syncthreads();
  }
  #pragma unroll
  for (int i=0;i<4;i++){
    int row = mt*64 + ty*4 + i;
    #pragma unroll
    for (int j=0;j<4;j++){
      int col = nt*64 + tx*4 + j;
      if (row<2056 && col<514) C[(size_t)row*514+col] = acc[i][j];
    }
  }
}

// ---------------- assemble A[u][g][576] = C + Whh block (zero-padded) ----------------
__global__ void k_assemble(const float* __restrict__ C, const float* __restrict__ whf,
                           const float* __restrict__ whb, float* __restrict__ A){
  int idx = blockIdx.x*256+threadIdx.x;
  if (idx >= 528*4*576) return;
  int k = idx % 576;
  int g = (idx/576)&3;
  int u = idx/2304;
  float v = 0.f;
  if (u < 514 && k < 514){
    int j = (u<257)? u : u-257;
    int row = ((u<257)?0:1028) + g*257 + j;
    v = C[(size_t)row*514 + k];
    if (u<257){ if (k<257) v += whf[(size_t)(g*257+j)*257 + k]; }
    else      { if (k>=257) v += whb[(size_t)(g*257+j)*257 + (k-257)]; }
  }
  A[idx] = v;
}

// ---------------- d[u][g] = wih_row . lin_b + bih + bhh (wave per row) ----------------
__global__ void k_dvec(const float* __restrict__ wihf, const float* __restrict__ wihb,
                       const float* __restrict__ bihf, const float* __restrict__ bhhf,
                       const float* __restrict__ bihb, const float* __restrict__ bhhb,
                       const float* __restrict__ lb, float* __restrict__ dv){
  int row = blockIdx.x*4 + (threadIdx.x>>6);   // row = u*4+g, 2112 rows
  if (row >= 528*4) return;
  int u = row>>2, g = row&3;
  int lane = threadIdx.x & 63;
  float s = 0.f;
  float v = 0.f;
  if (u < 514){
    int j = (u<257)? u : u-257;
    int r = g*257+j;
    const float* wr = ((u<257)? wihf : wihb) + (size_t)r*257;
    for (int m=lane;m<257;m+=64) s += wr[m]*lb[m];
    #pragma unroll
    for (int off=32; off; off>>=1) s += __shfl_xor(s, off, 64);
    v = s + ((u<257) ? (bihf[r]+bhhf[r]) : (bihb[r]+bhhb[r]));
  }
  if (lane == 0) dv[row] = v;
}

// ---------------- encoder (h0=c0=0 so whh term vanishes) ----------------
__global__ void k_enc_gates(const float* __restrict__ wf, const float* __restrict__ wb,
                            const float* __restrict__ bihf, const float* __restrict__ bhhf,
                            const float* __restrict__ bihb, const float* __restrict__ bhhb,
                            const float* __restrict__ feat, float* __restrict__ gates){
  __shared__ float fs[128];
  int tid = threadIdx.x;
  if (tid < 128) fs[tid] = feat[tid];
  __syncthreads();
  int r = blockIdx.x*256 + tid;
  if (r >= 2056) return;
  const float* wr; float bias;
  if (r < 1028){ wr = wf + (size_t)r*128; bias = bihf[r]+bhhf[r]; }
  else { int rr = r-1028; wr = wb + (size_t)rr*128; bias = bihb[rr]+bhhb[rr]; }
  float s = bias;
  for (int m=0;m<128;m++) s += wr[m]*fs[m];
  gates[r] = s;
}

// writes Ydec row 0 (528 entries: 514 real + 14 zeros) and cinit (528)
__global__ void k_enc_point(const float* __restrict__ gates, float* __restrict__ ydec0,
                            float* __restrict__ cinit){
  int u = blockIdx.x*256+threadIdx.x;
  if (u >= 528) return;
  float h = 0.f, c = 0.f;
  if (u < 514){
    int j = (u<257)? u : u-257;
    int base = (u<257)? 0 : 1028;
    float gi = gates[base + j];
    float gg = gates[base + 514 + j];
    float go = gates[base + 771 + j];
    c = sigm(gi)*tanh_f(gg);
    h = sigm(go)*tanh_f(c);
  }
  ydec0[u] = h; cinit[u] = c;
}

// ---------------- persistent fused decoder: pipelined poison-poll sync ----------------
#define LOADSET(dst) \
  { _Pragma("unroll") for (int j=0;j<9;j++) \
      dst[j] = __hip_atomic_load(rowp + tid + j*64, __ATOMIC_RELAXED, __HIP_MEMORY_SCOPE_AGENT); }
#define CHECKSET(src, okvar) \
  { bool _ok = true; \
    _Pragma("unroll") for (int j=0;j<9;j++){ int _i = tid + j*64; if (_i < 528 && src[j] == POISON) _ok = false; } \
    okvar = __all(_ok); }
#define COPYOUT(src) \
  { _Pragma("unroll") for (int j=0;j<9;j++){ int _i = tid + j*64; ((unsigned int*)ysb)[_i] = (_i < 528) ? src[j] : 0u; } }

__global__ __launch_bounds__(256,1) void k_decode(
    const float* __restrict__ A, const float* __restrict__ dv,
    const float* __restrict__ cinit, float* __restrict__ Ydec)
{
  const int tid = threadIdx.x;
  const int u0 = tid>>4;
  const int u = blockIdx.x*16 + u0;
  const int q = tid & 15;
  float w[4][36];
  {
    const float* base = A + (size_t)u*4*576 + q*36;
    #pragma unroll
    for (int g=0; g<4; g++){
      #pragma unroll
      for (int i=0;i<36;i+=4){
        float4 v = *(const float4*)(base + g*576 + i);
        w[g][i]=v.x; w[g][i+1]=v.y; w[g][i+2]=v.z; w[g][i+3]=v.w;
      }
    }
  }
  const float4 dg = *(const float4*)(dv + u*4);
  float c = cinit[u];
  __shared__ __align__(16) float ys[576];
  __shared__ float hs[16];
  for (int step=0; step<128; step++){
    float* ysb = ys;
    if (tid < 64){
      const unsigned int* rowp = (const unsigned int*)(Ydec + (size_t)step*576);
      unsigned int va[9], vb[9], vc[9];
      int ok;
      LOADSET(va);
      LOADSET(vb);
      for(;;){
        LOADSET(vc);
        CHECKSET(va, ok); if (ok){ COPYOUT(va); break; }
        LOADSET(va);
        CHECKSET(vb, ok); if (ok){ COPYOUT(vb); break; }
        LOADSET(vb);
        CHECKSET(vc, ok); if (ok){ COPYOUT(vc); break; }
      }
    }
    __syncthreads();
    float s0=0.f, s1=0.f, s2=0.f, s3=0.f;
    const float4* yl4 = (const float4*)&ysb[q*36];
    #pragma unroll
    for (int i=0;i<9;i++){
      float4 yv = yl4[i];
      s0 += w[0][i*4]*yv.x + w[0][i*4+1]*yv.y + w[0][i*4+2]*yv.z + w[0][i*4+3]*yv.w;
      s1 += w[1][i*4]*yv.x + w[1][i*4+1]*yv.y + w[1][i*4+2]*yv.z + w[1][i*4+3]*yv.w;
      s2 += w[2][i*4]*yv.x + w[2][i*4+1]*yv.y + w[2][i*4+2]*yv.z + w[2][i*4+3]*yv.w;
      s3 += w[3][i*4]*yv.x + w[3][i*4+1]*yv.y + w[3][i*4+2]*yv.z + w[3][i*4+3]*yv.w;
    }
    #pragma unroll
    for (int off=8; off; off>>=1){
      s0 += __shfl_xor(s0, off, 64);
      s1 += __shfl_xor(s1, off, 64);
      s2 += __shfl_xor(s2, off, 64);
      s3 += __shfl_xor(s3, off, 64);
    }
    // butterfly leaves full sums in every lane of the 16-group
    float ci = sigm(s1+dg.y)*c + sigm(s0+dg.x)*tanh_f(s2+dg.z);
    c = ci;
    float h = sigm(s3+dg.w)*tanh_f(ci);
    if (q == 0) hs[u0] = h;
    __syncthreads();
    if (tid < 16){
      __hip_atomic_store((unsigned int*)(Ydec + (size_t)(step+1)*576) + blockIdx.x*16 + tid,
                         __float_as_uint(hs[tid]), __ATOMIC_RELAXED, __HIP_MEMORY_SCOPE_AGENT);
    }
  }
}

// ---------------- out[t][m] = lin_b[m] + lin_w[m] . y_{t+1} ----------------
__global__ __launch_bounds__(256) void k_final(const float* __restrict__ Ydec, const float* __restrict__ lw,
                        const float* __restrict__ lb, float* __restrict__ out){
  __shared__ float ysl[514];
  int t = blockIdx.x, tid = threadIdx.x;
  for (int i=tid;i<514;i+=256) ysl[i] = Ydec[(size_t)(t+1)*576+i];
  __syncthreads();
  for (int m=tid; m<257; m+=256){
    float s = lb[m];
    const float* wr = lw + (size_t)m*514;
    for (int k=0;k<514;k++) s += wr[k]*ysl[k];
    out[t*257+m] = s;
  }
}

extern "C" void kernel_launch(void* const* d_in, const int* in_sizes, int n_in,
                              void* d_out, int out_size, void* d_ws, size_t ws_size,
                              hipStream_t stream){
  const float* src  = (const float*)d_in[0];
  const float* c1w = (const float*)d_in[1];  const float* c1b = (const float*)d_in[2];
  const float* c2w = (const float*)d_in[3];  const float* c2b = (const float*)d_in[4];
  const float* c3w = (const float*)d_in[5];  const float* c3b = (const float*)d_in[6];
  const float* c4w = (const float*)d_in[7];  const float* c4b = (const float*)d_in[8];
  const float* c5w = (const float*)d_in[9];  const float* c5b = (const float*)d_in[10];
  const float* c6w = (const float*)d_in[11]; const float* c6b = (const float*)d_in[12];
  const float* fc1w= (const float*)d_in[13]; const float* fc1b= (const float*)d_in[14];
  const float* fc2w= (const float*)d_in[15]; const float* fc2b= (const float*)d_in[16];
  const float* fc3w= (const float*)d_in[17]; const float* fc3b= (const float*)d_in[18];
  const float* ewihf=(const float*)d_in[19];
  const float* ebihf=(const float*)d_in[21]; const float* ebhhf=(const float*)d_in[22];
  const float* ewihb=(const float*)d_in[23];
  const float* ebihb=(const float*)d_in[25]; const float* ebhhb=(const float*)d_in[26];
  const float* dwihf=(const float*)d_in[27]; const float* dwhhf=(const float*)d_in[28];
  const float* dbihf=(const float*)d_in[29]; const float* dbhhf=(const float*)d_in[30];
  const float* dwihb=(const float*)d_in[31]; const float* dwhhb=(const float*)d_in[32];
  const float* dbihb=(const float*)d_in[33]; const float* dbhhb=(const float*)d_in[34];
  const float* lw  = (const float*)d_in[35]; const float* lbv = (const float*)d_in[36];
  float* out = (float*)d_out;

  float* W = (float*)d_ws;
  float* cinit = W + 0;          // 528
  float* gates = W + 528;        // 2056
  float* dv    = W + 2584;       // 2112
  float* A     = W + 4704;       // 528*4*576 = 1216512
  float* C     = W + 1221216;    // 2056*514 = 1056784
  float* Ydec  = W + 2278000;    // 129*576 = 74304
  float* part  = W + 2352304;    // up to 1179648
  float* X0    = W + 3531952;    // 294912
  float* X1    = W + 3826864;    // 247808
  float* xfc   = W + 4074672;    // 51200
  float* f1    = W + 4125872;    // 2048
  float* f2    = W + 4127920;    // 512
  float* feat  = W + 4128432;    // 128

  // poison Ydec rows 1..128 (decode's data-flow sync polls against this)
  k_setup<<<288,256,0,stream>>>((unsigned int*)Ydec);

  // decoder fused-weight precompute
  k_gemm_wl<<<33*9,256,0,stream>>>(dwihf, dwihb, lw, C);
  k_assemble<<<DIV_UP(528*4*576,256),256,0,stream>>>(C, dwhhf, dwhhb, A);
  k_dvec<<<528,256,0,stream>>>(dwihf, dwihb, dbihf, dbhhf, dbihb, dbhhb, lbv, dv);

  // CNN chain
  k_pool1<<<128,256,0,stream>>>(src, X0);
  k_conv_gemm<3><<<1*15*18,256,0,stream>>>(X0, c1w, part, 32,32,32,  64,30,30, 18, 16);
  k_conv_reduce<<<DIV_UP(64*900,256),256,0,stream>>>(part, c1b, X1, 64, 900, 18);
  k_conv_gemm<3><<<2*13*9,256,0,stream>>>(X1, c2w, part, 64,30,30, 128,28,28, 9, 64);
  k_conv_reduce<<<DIV_UP(128*784,256),256,0,stream>>>(part, c2b, X0, 128, 784, 9);
  k_conv_gemm<3><<<4*11*6,256,0,stream>>>(X0, c3w, part, 128,28,28, 256,26,26, 6, 192);
  k_conv_reduce<<<DIV_UP(256*676,256),256,0,stream>>>(part, c3b, X1, 256, 676, 6);
  k_conv_gemm<3><<<8*9*4,256,0,stream>>>(X1, c4w, part, 256,26,26, 512,24,24, 4, 576);
  k_conv_reduce<<<DIV_UP(512*576,256),256,0,stream>>>(part, c4b, X0, 512, 576, 4);
  k_conv_gemm<3><<<8*8*4,256,0,stream>>>(X0, c5w, part, 512,24,24, 512,22,22, 4, 1152);
  k_conv_reduce<<<DIV_UP(512*484,256),256,0,stream>>>(part, c5b, X1, 512, 484, 4);
  k_conv_gemm<2><<<8*7*4,256,0,stream>>>(X1, c6w, part, 512,22,22, 512,21,21, 4, 512);
  k_conv_reduce<<<DIV_UP(512*441,256),256,0,stream>>>(part, c6b, X0, 512, 441, 4);
  k_pool2<<<200,256,0,stream>>>(X0, xfc);

  // FC stack
  k_fc<<<2048,256,0,stream>>>(fc1w, xfc, fc1b, f1, 51200, 1);
  k_fc<<<512,256,0,stream>>>(fc2w, f1, fc2b, f2, 2048, 1);
  k_fc<<<128,256,0,stream>>>(fc3w, f2, fc3b, feat, 512, 0);

  // encoder (zero initial state => whh term drops)
  k_enc_gates<<<9,256,0,stream>>>(ewihf, ewihb, ebihf, ebhhf, ebihb, ebhhb, feat, gates);
  k_enc_point<<<3,256,0,stream>>>(gates, Ydec, cinit);

  // persistent decoder: 128 steps, pipelined data-flow sync
  k_decode<<<DEC_NWG,256,0,stream>>>(A, dv, cinit, Ydec);

  // output projection
  k_final<<<128,256,0,stream>>>(Ydec, lw, lbv, out);
}